// Round 12
// baseline (97.347 us; speedup 1.0000x reference)
//
#include <hip/hip_runtime.h>

struct PrepPtrs { const float* W[7]; const float* Bv[7]; const float* F; const float* fb; };

// state-chunk swizzle (KA/KB): fold bits 3-4 into bits 0-1
__device__ __forceinline__ int cz(int c) { return c ^ ((c >> 3) & 3); }

__device__ __forceinline__ float4 relu4(float4 a) {
  return make_float4(fmaxf(a.x,0.f), fmaxf(a.y,0.f), fmaxf(a.z,0.f), fmaxf(a.w,0.f));
}
__device__ __forceinline__ void fma4(float4& acc, float s, const float4& wv) {
  acc.x = fmaf(s, wv.x, acc.x); acc.y = fmaf(s, wv.y, acc.y);
  acc.z = fmaf(s, wv.z, acc.z); acc.w = fmaf(s, wv.w, acc.w);
}

// ---------------- prep: pack weights into 80-float (k,th) entries (unchanged) ----------
__global__ void bfly_prep(PrepPtrs P, float* __restrict__ wt) {
  int e = blockIdx.x * 256 + threadIdx.x;
  if (e >= 510 * 68) return;
  int ent = e / 68, r = e % 68, dd = r & 3;
  float v; int dst;
  if (ent < 62) {
    dst = ent * 80 + r;
    if (ent < 60) {
      int lvl, base;
      if (ent < 4)       { lvl = 1; base = 0;  }
      else if (ent < 12) { lvl = 2; base = 4;  }
      else if (ent < 28) { lvl = 3; base = 12; }
      else               { lvl = 4; base = 28; }
      int k = (ent - base) >> 1, th = ent & 1;
      if (r < 64) { int s = r >> 5, c = (r >> 2) & 7;
        v = P.W[lvl-1][k*128 + s*64 + c*8 + th*4 + dd]; }
      else v = P.Bv[lvl-1][k*8 + th*4 + dd];
    } else {
      int th = ent - 60;
      if (r < 64) { int f = r >> 2; v = P.F[f*8 + th*4 + dd]; }
      else v = P.fb[th*4 + dd];
    }
  } else {
    int eb = ent - 62;                 // 0..447
    int q = eb / 56, rem = eb % 56;
    int lvl, Kl, base;
    if (rem < 8)       { lvl = 5; Kl = 4;  base = 0;  }
    else if (rem < 24) { lvl = 6; Kl = 8;  base = 8;  }
    else               { lvl = 7; Kl = 16; base = 24; }
    int rr = rem - base, lk = rr >> 1, th = rr & 1;
    int kg = q * Kl + lk;
    if (r < 64) { int s = r >> 5, c = (r >> 2) & 7;
      v = P.W[lvl-1][kg*128 + s*64 + c*8 + th*4 + dd]; }
    else v = P.Bv[lvl-1][kg*8 + th*4 + dd];
    dst = 4960 + eb * 80 + r;
  }
  wt[dst] = v;
}

// ---------------- KA: conv + levels 1..4, SGPR weights (R10 version) ----------------
template<int L>
__device__ __forceinline__ void ka_level(const float4* __restrict__ src,
                                         float4* __restrict__ dst,
                                         const float4* __restrict__ wt4,
                                         int lane, int wq, int th) {
  constexpr int Kc = 1 << L, Tc = 1024 >> L;
  constexpr int entBase = (Kc - 2) * 2;
  constexpr int kIters = (L <= 2) ? 1 : (1 << (L - 2));
  constexpr int tIters = 4 / kIters;
#pragma unroll
  for (int ik = 0; ik < kIters; ++ik) {
    int k;
    if constexpr (L == 1) k = wq & 1;
    else if constexpr (L == 2) k = wq;
    else k = wq + 4 * ik;
    const float4* e4 = wt4 + (entBase + k * 2 + th) * 20;   // uniform -> s_load
    const int kp = k >> 1;
#pragma unroll
    for (int it = 0; it < tIters; ++it) {
      int t;
      if constexpr (L == 1) t = lane + (wq >> 1) * 64 + it * 128;
      else if constexpr (L == 2) t = lane + it * 64;
      else if constexpr (L == 3) t = lane + it * 64;
      else t = lane;
      int pb = kp * (2 * Tc) + 2 * t;
      float4 A0 = src[cz(pb)],        C0 = src[cz(pb + 1)];
      float4 A1 = src[cz(pb + 1024)], C1 = src[cz(pb + 1025)];
      float4 a = e4[16];
      fma4(a, A0.x, e4[0]);  fma4(a, A0.y, e4[1]);  fma4(a, A0.z, e4[2]);  fma4(a, A0.w, e4[3]);
      fma4(a, A1.x, e4[4]);  fma4(a, A1.y, e4[5]);  fma4(a, A1.z, e4[6]);  fma4(a, A1.w, e4[7]);
      fma4(a, C0.x, e4[8]);  fma4(a, C0.y, e4[9]);  fma4(a, C0.z, e4[10]); fma4(a, C0.w, e4[11]);
      fma4(a, C1.x, e4[12]); fma4(a, C1.y, e4[13]); fma4(a, C1.z, e4[14]); fma4(a, C1.w, e4[15]);
      dst[cz(th * 1024 + k * Tc + t)] = relu4(a);
    }
  }
}

__global__ __launch_bounds__(512, 2) void bfly_ka(
    const float* __restrict__ x, const float* __restrict__ wt,
    float* __restrict__ st1)
{
  __shared__ float4 sA[2048], sB[2048];
  const int tid = threadIdx.x, b = blockIdx.x;
  const int lane = tid & 63;
  const int wv = __builtin_amdgcn_readfirstlane(tid >> 6);
  const int th = wv & 1, wq = wv >> 1;
  const float4* wt4 = (const float4*)wt;

  {
    const float4* e4 = wt4 + (60 + th) * 20;
    const float* xb = x + (size_t)b * 16384;
#pragma unroll
    for (int i = 0; i < 4; ++i) {
      int n = lane + wq * 64 + i * 256;
      const float4* xr = (const float4*)(xb + n * 16);
      float4 x0 = xr[0], x1 = xr[1], x2 = xr[2], x3 = xr[3];
      float4 a = e4[16];
      fma4(a, x0.x, e4[0]);  fma4(a, x0.y, e4[1]);  fma4(a, x0.z, e4[2]);  fma4(a, x0.w, e4[3]);
      fma4(a, x1.x, e4[4]);  fma4(a, x1.y, e4[5]);  fma4(a, x1.z, e4[6]);  fma4(a, x1.w, e4[7]);
      fma4(a, x2.x, e4[8]);  fma4(a, x2.y, e4[9]);  fma4(a, x2.z, e4[10]); fma4(a, x2.w, e4[11]);
      fma4(a, x3.x, e4[12]); fma4(a, x3.y, e4[13]); fma4(a, x3.z, e4[14]); fma4(a, x3.w, e4[15]);
      sA[cz(th * 1024 + n)] = relu4(a);
    }
  }
  __syncthreads();
  ka_level<1>(sA, sB, wt4, lane, wq, th); __syncthreads();
  ka_level<2>(sB, sA, wt4, lane, wq, th); __syncthreads();
  ka_level<3>(sA, sB, wt4, lane, wq, th); __syncthreads();
  ka_level<4>(sB, sA, wt4, lane, wq, th); __syncthreads();

  float4* o4 = (float4*)st1;
#pragma unroll
  for (int it = 0; it < 4; ++it) {
    int o = tid + it * 512;
    int t4 = o & 63, k4 = (o >> 6) & 15, h = o >> 10;
    o4[((size_t)(h * 16 + k4) * 1024 + b) * 64 + t4] = sA[cz(o)];
  }
}

// ---------------- KB: levels 5..7 (unchanged) ----------------
template<int LV>
__device__ __forceinline__ void kb_level(const float4* __restrict__ src,
                                         float4* __restrict__ dst,
                                         const float4* __restrict__ wb4,
                                         int lane, int wv) {
  constexpr int Kc = 1 << (LV - 3);
  constexpr int Tc = 128 / Kc;
  constexpr int Tp = 256 / Kc;
  constexpr int entB = (LV == 5) ? 0 : (LV == 6) ? 8 : 24;
  constexpr int kIters = Kc / 4;
  constexpr int nIt = 4 / kIters;
  const int th = wv & 1, w2 = wv >> 1;
#pragma unroll
  for (int ik = 0; ik < kIters; ++ik) {
    const int lk = w2 + 4 * ik;
    const float4* e4 = wb4 + (entB + lk * 2 + th) * 20;   // uniform -> s_load
    const int lkp = lk >> 1;
#pragma unroll
    for (int it = 0; it < nIt; ++it) {
      int t, bb;
      if constexpr (LV == 5)      { t = lane & 31; bb = (lane >> 5) + it * 2; }
      else if constexpr (LV == 6) { t = lane & 15; bb = (lane >> 4) + it * 4; }
      else                        { t = lane & 7;  bb = lane >> 3; }
      int pb = bb * 256 + lkp * Tp + 2 * t;
      float4 A0 = src[cz(pb)],       C0 = src[cz(pb + 1)];
      float4 A1 = src[cz(pb + 128)], C1 = src[cz(pb + 129)];
      float4 a = e4[16];
      fma4(a, A0.x, e4[0]);  fma4(a, A0.y, e4[1]);  fma4(a, A0.z, e4[2]);  fma4(a, A0.w, e4[3]);
      fma4(a, A1.x, e4[4]);  fma4(a, A1.y, e4[5]);  fma4(a, A1.z, e4[6]);  fma4(a, A1.w, e4[7]);
      fma4(a, C0.x, e4[8]);  fma4(a, C0.y, e4[9]);  fma4(a, C0.z, e4[10]); fma4(a, C0.w, e4[11]);
      fma4(a, C1.x, e4[12]); fma4(a, C1.y, e4[13]); fma4(a, C1.z, e4[14]); fma4(a, C1.w, e4[15]);
      dst[cz(bb * 256 + th * 128 + lk * Tc + t)] = relu4(a);
    }
  }
}

__global__ __launch_bounds__(512, 2) void bfly_kb(
    const float* __restrict__ st1, const float* __restrict__ wt,
    float* __restrict__ st2)
{
  __shared__ float4 s0[2048], s1[2048];
  const int tid = threadIdx.x;
  const int q = blockIdx.x, bt = blockIdx.y;
  const int lane = tid & 63;
  const int wv = __builtin_amdgcn_readfirstlane(tid >> 6);
  const float4* wb4 = (const float4*)wt + 1240 + q * 56 * 20;
  const float4* i4 = (const float4*)st1;

#pragma unroll
  for (int it = 0; it < 4; ++it) {
    int o = tid + it * 512;
    int t4 = o & 63, lk4 = (o >> 6) & 1, h = (o >> 7) & 1, bl = o >> 8;
    float4 v = i4[((size_t)(h * 16 + 2 * q + lk4) * 1024 + bt * 8 + bl) * 64 + t4];
    s0[cz(bl * 256 + h * 128 + lk4 * 64 + t4)] = v;
  }
  __syncthreads();
  kb_level<5>(s0, s1, wb4, lane, wv); __syncthreads();
  kb_level<6>(s1, s0, wb4, lane, wv); __syncthreads();
  kb_level<7>(s0, s1, wb4, lane, wv); __syncthreads();

  float4* o4 = (float4*)st2;
#pragma unroll
  for (int it = 0; it < 4; ++it) {
    int o = tid + it * 512;
    int bl = o & 7, t7 = (o >> 3) & 7, h = (o >> 6) & 1, lk7 = o >> 7;
    float4 v = s1[cz(bl * 256 + h * 128 + lk7 * 8 + t7)];
    o4[((size_t)((16 * q + lk7) * 8 + t7) * 2 + h) * 1024 + bt * 8 + bl] = v;
  }
}

// ---------------- KC: levels 8..10 + dense, 64-batch tiles, reg-resident weights ------
// state chunk = h*512 + row*64 + bb
struct Wmat {
  float4 w0,w1,w2,w3,w4,w5,w6,w7,w8,w9,w10,w11,w12,w13,w14,w15,b;
};
__device__ __forceinline__ Wmat loadWm(const float* __restrict__ swt,
                                       int woff, int boff, int k_l, int th) {
  Wmat m;
  const float4* p = (const float4*)(swt + woff + k_l * 128 + th * 4);
  m.w0 = p[0];  m.w1 = p[2];  m.w2 = p[4];  m.w3 = p[6];
  m.w4 = p[8];  m.w5 = p[10]; m.w6 = p[12]; m.w7 = p[14];
  m.w8 = p[16]; m.w9 = p[18]; m.w10 = p[20]; m.w11 = p[22];
  m.w12 = p[24]; m.w13 = p[26]; m.w14 = p[28]; m.w15 = p[30];
  m.b = *(const float4*)(swt + boff + k_l * 8 + th * 4);
  return m;
}
__device__ __forceinline__ float4 matApply(const Wmat& m, float4 A0, float4 A1,
                                           float4 C0, float4 C1) {
  float4 a = m.b;
  fma4(a, A0.x, m.w0);  fma4(a, A0.y, m.w1);  fma4(a, A0.z, m.w2);  fma4(a, A0.w, m.w3);
  fma4(a, A1.x, m.w4);  fma4(a, A1.y, m.w5);  fma4(a, A1.z, m.w6);  fma4(a, A1.w, m.w7);
  fma4(a, C0.x, m.w8);  fma4(a, C0.y, m.w9);  fma4(a, C0.z, m.w10); fma4(a, C0.w, m.w11);
  fma4(a, C1.x, m.w12); fma4(a, C1.y, m.w13); fma4(a, C1.z, m.w14); fma4(a, C1.w, m.w15);
  return relu4(a);
}

__global__ __launch_bounds__(512, 2) void bfly_kc(
    const float* __restrict__ st,
    const float* __restrict__ W8, const float* __restrict__ B8,
    const float* __restrict__ W9, const float* __restrict__ B9,
    const float* __restrict__ W10, const float* __restrict__ B10,
    const float* __restrict__ fea, float* __restrict__ out)
{
  __shared__ float4 sA[1024], sB[1024];      // 64 batches x 16 chunk-rows
  __shared__ float swt[2928];
  const int tid = threadIdx.x;
  const int j = blockIdx.x, b0 = blockIdx.y * 64;
  const int bb = tid & 63, grp = tid >> 6;   // 8 groups of 64

  { // stage state: [h][t][bb]; global runs of 64 f4 = 1KB
    const float4* s4 = (const float4*)st;
#pragma unroll
    for (int it = 0; it < 2; ++it) {
      int idx = tid + it * 512;
      int bl = idx & 63, h = (idx >> 6) & 1, t = idx >> 7;
      sA[h * 512 + t * 64 + bl] = s4[((size_t)((j * 8 + t) * 2 + h)) * 1024 + b0 + bl];
    }
  }
  { // weights staging (contiguous)
    float4* d = (float4*)swt;
    for (int i = tid; i < 64;  i += 512) d[i]       = ((const float4*)(W8  + j*256 ))[i];
    for (int i = tid; i < 128; i += 512) d[64+i]    = ((const float4*)(W9  + j*512 ))[i];
    for (int i = tid; i < 256; i += 512) d[192+i]   = ((const float4*)(W10 + j*1024))[i];
    if (tid < 4)  d[448+tid] = ((const float4*)(B8  + j*16))[tid];
    if (tid < 8)  d[452+tid] = ((const float4*)(B9  + j*32))[tid];
    if (tid < 16) d[460+tid] = ((const float4*)(B10 + j*64))[tid];
    for (int i = tid; i < 256; i += 512) d[476+i]   = ((const float4*)(fea + j*1024))[i];
  }
  __syncthreads();

  { // level 8: sA(v7, t=0..3 local rows 0..7) -> sB rows 2t+k; grp=(h,k,ti)
    int h = grp >> 2, k = (grp >> 1) & 1, ti = grp & 1;
    Wmat m = loadWm(swt, 0, 1792, k, h);
#pragma unroll
    for (int i = 0; i < 2; ++i) {
      int t = ti + 2 * i;
      float4 A0 = sA[(2*t) * 64 + bb],     A1 = sA[512 + (2*t) * 64 + bb];
      float4 C0 = sA[(2*t+1) * 64 + bb],   C1 = sA[512 + (2*t+1) * 64 + bb];
      sB[h * 512 + (2*t + k) * 64 + bb] = matApply(m, A0, A1, C0, C1);
    }
  }
  __syncthreads();
  { // level 9: sB -> sA ; parents p0 = 4t9 + (k9>>1), p1 = p0+2
    int h = grp >> 2, k9 = grp & 3;
    Wmat m = loadWm(swt, 256, 1808, k9, h);
#pragma unroll
    for (int t9 = 0; t9 < 2; ++t9) {
      int p0 = 4 * t9 + (k9 >> 1), p1 = p0 + 2;
      float4 A0 = sB[p0 * 64 + bb], A1 = sB[512 + p0 * 64 + bb];
      float4 C0 = sB[p1 * 64 + bb], C1 = sB[512 + p1 * 64 + bb];
      sA[h * 512 + (t9 * 4 + k9) * 64 + bb] = matApply(m, A0, A1, C0, C1);
    }
  }
  __syncthreads();
  { // level 10: sA -> sB ; k10 = grp; parents p0 = k10>>1, p1 = p0+4
    int k10 = grp;
    int p0 = k10 >> 1, p1 = p0 + 4;
    float4 A0 = sA[p0 * 64 + bb], A1 = sA[512 + p0 * 64 + bb];
    float4 C0 = sA[p1 * 64 + bb], C1 = sA[512 + p1 * 64 + bb];
#pragma unroll 1
    for (int h = 0; h < 2; ++h) {
      Wmat m = loadWm(swt, 768, 1840, k10, h);
      sB[h * 512 + k10 * 64 + bb] = matApply(m, A0, A1, C0, C1);
    }
  }
  __syncthreads();
  { // dense: thread owns (k,fq); fea hoisted once; iterate 4 batches
    int cc = tid & 31, bgrp = tid >> 5;      // cc -> (k,fq); 16 b-groups
    int k = cc >> 2, fq = cc & 3;
    const float* fp = swt + 1904 + k * 128 + fq * 4;
    float4 f0 = *(const float4*)(fp);        float4 f1 = *(const float4*)(fp + 16);
    float4 f2 = *(const float4*)(fp + 32);   float4 f3 = *(const float4*)(fp + 48);
    float4 f4_ = *(const float4*)(fp + 64);  float4 f5 = *(const float4*)(fp + 80);
    float4 f6 = *(const float4*)(fp + 96);   float4 f7 = *(const float4*)(fp + 112);
#pragma unroll
    for (int it = 0; it < 4; ++it) {
      int b_l = bgrp + it * 16;
      float4 s0v = sB[k * 64 + b_l];
      float4 s1v = sB[512 + k * 64 + b_l];
      float4 acc = make_float4(0.f, 0.f, 0.f, 0.f);
      fma4(acc, s0v.x, f0);  fma4(acc, s0v.y, f1);
      fma4(acc, s0v.z, f2);  fma4(acc, s0v.w, f3);
      fma4(acc, s1v.x, f4_); fma4(acc, s1v.y, f5);
      fma4(acc, s1v.z, f6);  fma4(acc, s1v.w, f7);
      *(float4*)(out + ((size_t)(b0 + b_l)) * 16384 + j * 128 + k * 16 + fq * 4) = acc;
    }
  }
}

extern "C" void kernel_launch(void* const* d_in, const int* in_sizes, int n_in,
                              void* d_out, int out_size, void* d_ws, size_t ws_size,
                              hipStream_t stream) {
  const float* x  = (const float*)d_in[0];
  PrepPtrs P;
  P.F  = (const float*)d_in[1];
  P.fb = (const float*)d_in[2];
  for (int l = 0; l < 7; ++l) {
    P.W[l]  = (const float*)d_in[3 + 2 * l];
    P.Bv[l] = (const float*)d_in[4 + 2 * l];
  }
  const float* W8  = (const float*)d_in[17];
  const float* B8  = (const float*)d_in[18];
  const float* W9  = (const float*)d_in[19];
  const float* B9  = (const float*)d_in[20];
  const float* W10 = (const float*)d_in[21];
  const float* B10 = (const float*)d_in[22];
  const float* fea = (const float*)d_in[23];
  float* wt  = (float*)d_ws;                 // packed KA/KB weight entries
  float* st2 = (float*)d_ws + 65536;         // 33.5 MB level-7 state [j][t][h][b]
  float* st1 = (float*)d_out;                // 33.5 MB level-4 state (KC overwrites d_out)
  float* out = (float*)d_out;

  bfly_prep<<<dim3(136), dim3(256), 0, stream>>>(P, wt);
  bfly_ka<<<dim3(1024), dim3(512), 0, stream>>>(x, wt, st1);
  bfly_kb<<<dim3(8, 128), dim3(512), 0, stream>>>(st1, wt, st2);
  bfly_kc<<<dim3(128, 16), dim3(512), 0, stream>>>(st2, W8, B8, W9, B9, W10, B10, fea, out);
}

// Round 13
// 93.041 us; speedup vs baseline: 1.0463x; 1.0463x over previous
//
#include <hip/hip_runtime.h>

struct PrepPtrs {
  const float* W[7]; const float* Bv[7]; const float* F; const float* fb;
  const float* W8; const float* B8; const float* W9; const float* B9;
  const float* W10; const float* B10;
};

// state-chunk swizzle (KA/KB): fold bits 3-4 into bits 0-1
__device__ __forceinline__ int cz(int c) { return c ^ ((c >> 3) & 3); }

__device__ __forceinline__ float4 relu4(float4 a) {
  return make_float4(fmaxf(a.x,0.f), fmaxf(a.y,0.f), fmaxf(a.z,0.f), fmaxf(a.w,0.f));
}
__device__ __forceinline__ void fma4(float4& acc, float s, const float4& wv) {
  acc.x = fmaf(s, wv.x, acc.x); acc.y = fmaf(s, wv.y, acc.y);
  acc.z = fmaf(s, wv.z, acc.z); acc.w = fmaf(s, wv.w, acc.w);
}

// ---------------- prep: pack ALL weights into 80-float (k,th) entries ----------------
// Entry = [16 x f4 W(s*8+c)] [f4 bias] [3 f4 pad]. Entry table (f4 idx = ent*20):
//   [0,60)    levels 1-4   (k*2+th within level, level bases 0/4/12/28)
//   [60,62)   conv         (th)
//   [62,510)  levels 5-7 by q  (q*56 + {lvl5:0, lvl6:8, lvl7:24} + lk*2+th)
//   [510,1022)   level 8   (k8*2+th),  k8  in [0,256)
//   [1022,2046)  level 9   (k9*2+th),  k9  in [0,512)
//   [2046,4094)  level 10  (k10*2+th), k10 in [0,1024)
__global__ void bfly_prep(PrepPtrs P, float* __restrict__ wt) {
  int e = blockIdx.x * 256 + threadIdx.x;
  if (e >= 4094 * 68) return;
  int ent = e / 68, r = e % 68, dd = r & 3;
  const float* Ws; const float* Bs; int th;
  if (ent < 62) {
    if (ent < 60) {
      int lvl, base;
      if (ent < 4)       { lvl = 1; base = 0;  }
      else if (ent < 12) { lvl = 2; base = 4;  }
      else if (ent < 28) { lvl = 3; base = 12; }
      else               { lvl = 4; base = 28; }
      int k = (ent - base) >> 1; th = ent & 1;
      Ws = P.W[lvl-1] + k*128; Bs = P.Bv[lvl-1] + k*8;
    } else {
      th = ent - 60; Ws = P.F; Bs = P.fb;
    }
  } else if (ent < 510) {
    int eb = ent - 62;
    int q = eb / 56, rem = eb % 56;
    int lvl, Kl, base;
    if (rem < 8)       { lvl = 5; Kl = 4;  base = 0;  }
    else if (rem < 24) { lvl = 6; Kl = 8;  base = 8;  }
    else               { lvl = 7; Kl = 16; base = 24; }
    int rr = rem - base; int lk = rr >> 1; th = rr & 1;
    int kg = q * Kl + lk;
    Ws = P.W[lvl-1] + kg*128; Bs = P.Bv[lvl-1] + kg*8;
  } else if (ent < 1022) {
    int ec = ent - 510; int k = ec >> 1; th = ec & 1;
    Ws = P.W8 + k*128; Bs = P.B8 + k*8;
  } else if (ent < 2046) {
    int ec = ent - 1022; int k = ec >> 1; th = ec & 1;
    Ws = P.W9 + k*128; Bs = P.B9 + k*8;
  } else {
    int ec = ent - 2046; int k = ec >> 1; th = ec & 1;
    Ws = P.W10 + k*128; Bs = P.B10 + k*8;
  }
  float v;
  if (r < 64) { int s = r >> 5, c = (r >> 2) & 7; v = Ws[s*64 + c*8 + th*4 + dd]; }
  else v = Bs[th*4 + dd];
  wt[ent * 80 + r] = v;
}

// ---------------- KA: conv + levels 1..4, SGPR weights (unchanged) ----------------
template<int L>
__device__ __forceinline__ void ka_level(const float4* __restrict__ src,
                                         float4* __restrict__ dst,
                                         const float4* __restrict__ wt4,
                                         int lane, int wq, int th) {
  constexpr int Kc = 1 << L, Tc = 1024 >> L;
  constexpr int entBase = (Kc - 2) * 2;
  constexpr int kIters = (L <= 2) ? 1 : (1 << (L - 2));
  constexpr int tIters = 4 / kIters;
#pragma unroll
  for (int ik = 0; ik < kIters; ++ik) {
    int k;
    if constexpr (L == 1) k = wq & 1;
    else if constexpr (L == 2) k = wq;
    else k = wq + 4 * ik;
    const float4* e4 = wt4 + (entBase + k * 2 + th) * 20;   // uniform -> s_load
    const int kp = k >> 1;
#pragma unroll
    for (int it = 0; it < tIters; ++it) {
      int t;
      if constexpr (L == 1) t = lane + (wq >> 1) * 64 + it * 128;
      else if constexpr (L == 2) t = lane + it * 64;
      else if constexpr (L == 3) t = lane + it * 64;
      else t = lane;
      int pb = kp * (2 * Tc) + 2 * t;
      float4 A0 = src[cz(pb)],        C0 = src[cz(pb + 1)];
      float4 A1 = src[cz(pb + 1024)], C1 = src[cz(pb + 1025)];
      float4 a = e4[16];
      fma4(a, A0.x, e4[0]);  fma4(a, A0.y, e4[1]);  fma4(a, A0.z, e4[2]);  fma4(a, A0.w, e4[3]);
      fma4(a, A1.x, e4[4]);  fma4(a, A1.y, e4[5]);  fma4(a, A1.z, e4[6]);  fma4(a, A1.w, e4[7]);
      fma4(a, C0.x, e4[8]);  fma4(a, C0.y, e4[9]);  fma4(a, C0.z, e4[10]); fma4(a, C0.w, e4[11]);
      fma4(a, C1.x, e4[12]); fma4(a, C1.y, e4[13]); fma4(a, C1.z, e4[14]); fma4(a, C1.w, e4[15]);
      dst[cz(th * 1024 + k * Tc + t)] = relu4(a);
    }
  }
}

__global__ __launch_bounds__(512, 2) void bfly_ka(
    const float* __restrict__ x, const float* __restrict__ wt,
    float* __restrict__ st1)
{
  __shared__ float4 sA[2048], sB[2048];
  const int tid = threadIdx.x, b = blockIdx.x;
  const int lane = tid & 63;
  const int wv = __builtin_amdgcn_readfirstlane(tid >> 6);
  const int th = wv & 1, wq = wv >> 1;
  const float4* wt4 = (const float4*)wt;

  {
    const float4* e4 = wt4 + (60 + th) * 20;
    const float* xb = x + (size_t)b * 16384;
#pragma unroll
    for (int i = 0; i < 4; ++i) {
      int n = lane + wq * 64 + i * 256;
      const float4* xr = (const float4*)(xb + n * 16);
      float4 x0 = xr[0], x1 = xr[1], x2 = xr[2], x3 = xr[3];
      float4 a = e4[16];
      fma4(a, x0.x, e4[0]);  fma4(a, x0.y, e4[1]);  fma4(a, x0.z, e4[2]);  fma4(a, x0.w, e4[3]);
      fma4(a, x1.x, e4[4]);  fma4(a, x1.y, e4[5]);  fma4(a, x1.z, e4[6]);  fma4(a, x1.w, e4[7]);
      fma4(a, x2.x, e4[8]);  fma4(a, x2.y, e4[9]);  fma4(a, x2.z, e4[10]); fma4(a, x2.w, e4[11]);
      fma4(a, x3.x, e4[12]); fma4(a, x3.y, e4[13]); fma4(a, x3.z, e4[14]); fma4(a, x3.w, e4[15]);
      sA[cz(th * 1024 + n)] = relu4(a);
    }
  }
  __syncthreads();
  ka_level<1>(sA, sB, wt4, lane, wq, th); __syncthreads();
  ka_level<2>(sB, sA, wt4, lane, wq, th); __syncthreads();
  ka_level<3>(sA, sB, wt4, lane, wq, th); __syncthreads();
  ka_level<4>(sB, sA, wt4, lane, wq, th); __syncthreads();

  float4* o4 = (float4*)st1;
#pragma unroll
  for (int it = 0; it < 4; ++it) {
    int o = tid + it * 512;
    int t4 = o & 63, k4 = (o >> 6) & 15, h = o >> 10;
    o4[((size_t)(h * 16 + k4) * 1024 + b) * 64 + t4] = sA[cz(o)];
  }
}

// ---------------- KB: levels 5..7 (unchanged) ----------------
template<int LV>
__device__ __forceinline__ void kb_level(const float4* __restrict__ src,
                                         float4* __restrict__ dst,
                                         const float4* __restrict__ wb4,
                                         int lane, int wv) {
  constexpr int Kc = 1 << (LV - 3);
  constexpr int Tc = 128 / Kc;
  constexpr int Tp = 256 / Kc;
  constexpr int entB = (LV == 5) ? 0 : (LV == 6) ? 8 : 24;
  constexpr int kIters = Kc / 4;
  constexpr int nIt = 4 / kIters;
  const int th = wv & 1, w2 = wv >> 1;
#pragma unroll
  for (int ik = 0; ik < kIters; ++ik) {
    const int lk = w2 + 4 * ik;
    const float4* e4 = wb4 + (entB + lk * 2 + th) * 20;   // uniform -> s_load
    const int lkp = lk >> 1;
#pragma unroll
    for (int it = 0; it < nIt; ++it) {
      int t, bb;
      if constexpr (LV == 5)      { t = lane & 31; bb = (lane >> 5) + it * 2; }
      else if constexpr (LV == 6) { t = lane & 15; bb = (lane >> 4) + it * 4; }
      else                        { t = lane & 7;  bb = lane >> 3; }
      int pb = bb * 256 + lkp * Tp + 2 * t;
      float4 A0 = src[cz(pb)],       C0 = src[cz(pb + 1)];
      float4 A1 = src[cz(pb + 128)], C1 = src[cz(pb + 129)];
      float4 a = e4[16];
      fma4(a, A0.x, e4[0]);  fma4(a, A0.y, e4[1]);  fma4(a, A0.z, e4[2]);  fma4(a, A0.w, e4[3]);
      fma4(a, A1.x, e4[4]);  fma4(a, A1.y, e4[5]);  fma4(a, A1.z, e4[6]);  fma4(a, A1.w, e4[7]);
      fma4(a, C0.x, e4[8]);  fma4(a, C0.y, e4[9]);  fma4(a, C0.z, e4[10]); fma4(a, C0.w, e4[11]);
      fma4(a, C1.x, e4[12]); fma4(a, C1.y, e4[13]); fma4(a, C1.z, e4[14]); fma4(a, C1.w, e4[15]);
      dst[cz(bb * 256 + th * 128 + lk * Tc + t)] = relu4(a);
    }
  }
}

__global__ __launch_bounds__(512, 2) void bfly_kb(
    const float* __restrict__ st1, const float* __restrict__ wt,
    float* __restrict__ st2)
{
  __shared__ float4 s0[2048], s1[2048];
  const int tid = threadIdx.x;
  const int q = blockIdx.x, bt = blockIdx.y;
  const int lane = tid & 63;
  const int wv = __builtin_amdgcn_readfirstlane(tid >> 6);
  const float4* wb4 = (const float4*)wt + 1240 + q * 56 * 20;
  const float4* i4 = (const float4*)st1;

#pragma unroll
  for (int it = 0; it < 4; ++it) {
    int o = tid + it * 512;
    int t4 = o & 63, lk4 = (o >> 6) & 1, h = (o >> 7) & 1, bl = o >> 8;
    float4 v = i4[((size_t)(h * 16 + 2 * q + lk4) * 1024 + bt * 8 + bl) * 64 + t4];
    s0[cz(bl * 256 + h * 128 + lk4 * 64 + t4)] = v;
  }
  __syncthreads();
  kb_level<5>(s0, s1, wb4, lane, wv); __syncthreads();
  kb_level<6>(s1, s0, wb4, lane, wv); __syncthreads();
  kb_level<7>(s0, s1, wb4, lane, wv); __syncthreads();

  float4* o4 = (float4*)st2;
#pragma unroll
  for (int it = 0; it < 4; ++it) {
    int o = tid + it * 512;
    int bl = o & 7, t7 = (o >> 3) & 7, h = (o >> 6) & 1, lk7 = o >> 7;
    float4 v = s1[cz(bl * 256 + h * 128 + lk7 * 8 + t7)];
    o4[((size_t)((16 * q + lk7) * 8 + t7) * 2 + h) * 1024 + bt * 8 + bl] = v;
  }
}

// ---------------- KC: levels 8..10 + dense, all-SGPR weights, no weight LDS ----------
// state chunk = h*512 + row*64 + bb (bb lane-minor -> conflict-free)
__global__ __launch_bounds__(512, 2) void bfly_kc(
    const float* __restrict__ st, const float* __restrict__ wt,
    const float* __restrict__ fea, float* __restrict__ out)
{
  __shared__ float4 sA[1024], sB[1024];
  const int tid = threadIdx.x;
  const int j = blockIdx.x, b0 = blockIdx.y * 64;
  const int bb = tid & 63;
  const int w = __builtin_amdgcn_readfirstlane(tid >> 6);
  const float4* wt4 = (const float4*)wt;

  { // stage state from st2[j][t][h][b]
    const float4* s4 = (const float4*)st;
#pragma unroll
    for (int it = 0; it < 2; ++it) {
      int idx = tid + it * 512;
      int bl = idx & 63, h = (idx >> 6) & 1, t = idx >> 7;
      sA[h * 512 + t * 64 + bl] = s4[((size_t)((j * 8 + t) * 2 + h)) * 1024 + b0 + bl];
    }
  }
  __syncthreads();

  auto mat = [&](const float4* e4, float4 A0, float4 A1, float4 C0, float4 C1) {
    float4 a = e4[16];
    fma4(a, A0.x, e4[0]);  fma4(a, A0.y, e4[1]);  fma4(a, A0.z, e4[2]);  fma4(a, A0.w, e4[3]);
    fma4(a, A1.x, e4[4]);  fma4(a, A1.y, e4[5]);  fma4(a, A1.z, e4[6]);  fma4(a, A1.w, e4[7]);
    fma4(a, C0.x, e4[8]);  fma4(a, C0.y, e4[9]);  fma4(a, C0.z, e4[10]); fma4(a, C0.w, e4[11]);
    fma4(a, C1.x, e4[12]); fma4(a, C1.y, e4[13]); fma4(a, C1.z, e4[14]); fma4(a, C1.w, e4[15]);
    return relu4(a);
  };

  // level 8: global k8 = 2j+k (k in {0,1}); slots s = th*8 + k*4 + t
#pragma unroll
  for (int ii = 0; ii < 2; ++ii) {
    int s = w + ii * 8;
    int th = s >> 3, k = (s >> 2) & 1, t = s & 3;
    const float4* e4 = wt4 + (510 + (2 * j + k) * 2 + th) * 20;   // uniform -> s_load
    float4 A0 = sA[(2*t) * 64 + bb],   A1 = sA[512 + (2*t) * 64 + bb];
    float4 C0 = sA[(2*t+1) * 64 + bb], C1 = sA[512 + (2*t+1) * 64 + bb];
    sB[th * 512 + (2*t + k) * 64 + bb] = mat(e4, A0, A1, C0, C1);
  }
  __syncthreads();
  // level 9: global k9 = 4j+k9l; slots s = th*8 + k9l*2 + t9
#pragma unroll
  for (int ii = 0; ii < 2; ++ii) {
    int s = w + ii * 8;
    int th = s >> 3, k9 = (s >> 1) & 3, t9 = s & 1;
    const float4* e4 = wt4 + (1022 + (4 * j + k9) * 2 + th) * 20;
    int p0 = 4 * t9 + (k9 >> 1), p1 = p0 + 2;
    float4 A0 = sB[p0 * 64 + bb], A1 = sB[512 + p0 * 64 + bb];
    float4 C0 = sB[p1 * 64 + bb], C1 = sB[512 + p1 * 64 + bb];
    sA[th * 512 + (t9 * 4 + k9) * 64 + bb] = mat(e4, A0, A1, C0, C1);
  }
  __syncthreads();
  // level 10: global k10 = 8j+k10l; slots s = th*8 + k10l
#pragma unroll
  for (int ii = 0; ii < 2; ++ii) {
    int s = w + ii * 8;
    int th = s >> 3, k10 = s & 7;
    const float4* e4 = wt4 + (2046 + (8 * j + k10) * 2 + th) * 20;
    int p0 = k10 >> 1, p1 = p0 + 4;
    float4 A0 = sA[p0 * 64 + bb], A1 = sA[512 + p0 * 64 + bb];
    float4 C0 = sA[p1 * 64 + bb], C1 = sA[512 + p1 * 64 + bb];
    sB[th * 512 + k10 * 64 + bb] = mat(e4, A0, A1, C0, C1);
  }
  __syncthreads();
  { // dense: thread owns (k,fq); fea hoisted from global (L2-resident); 4 batches
    int cc = tid & 31, bgrp = tid >> 5;
    int k = cc >> 2, fq = cc & 3;
    const float* fp = fea + (size_t)(j * 8 + k) * 128 + fq * 4;
    float4 f0 = *(const float4*)(fp);        float4 f1 = *(const float4*)(fp + 16);
    float4 f2 = *(const float4*)(fp + 32);   float4 f3 = *(const float4*)(fp + 48);
    float4 f4_ = *(const float4*)(fp + 64);  float4 f5 = *(const float4*)(fp + 80);
    float4 f6 = *(const float4*)(fp + 96);   float4 f7 = *(const float4*)(fp + 112);
#pragma unroll
    for (int it = 0; it < 4; ++it) {
      int b_l = bgrp + it * 16;
      float4 s0v = sB[k * 64 + b_l];
      float4 s1v = sB[512 + k * 64 + b_l];
      float4 acc = make_float4(0.f, 0.f, 0.f, 0.f);
      fma4(acc, s0v.x, f0);  fma4(acc, s0v.y, f1);
      fma4(acc, s0v.z, f2);  fma4(acc, s0v.w, f3);
      fma4(acc, s1v.x, f4_); fma4(acc, s1v.y, f5);
      fma4(acc, s1v.z, f6);  fma4(acc, s1v.w, f7);
      *(float4*)(out + ((size_t)(b0 + b_l)) * 16384 + j * 128 + k * 16 + fq * 4) = acc;
    }
  }
}

extern "C" void kernel_launch(void* const* d_in, const int* in_sizes, int n_in,
                              void* d_out, int out_size, void* d_ws, size_t ws_size,
                              hipStream_t stream) {
  const float* x  = (const float*)d_in[0];
  PrepPtrs P;
  P.F  = (const float*)d_in[1];
  P.fb = (const float*)d_in[2];
  for (int l = 0; l < 7; ++l) {
    P.W[l]  = (const float*)d_in[3 + 2 * l];
    P.Bv[l] = (const float*)d_in[4 + 2 * l];
  }
  P.W8  = (const float*)d_in[17];
  P.B8  = (const float*)d_in[18];
  P.W9  = (const float*)d_in[19];
  P.B9  = (const float*)d_in[20];
  P.W10 = (const float*)d_in[21];
  P.B10 = (const float*)d_in[22];
  const float* fea = (const float*)d_in[23];
  float* wt  = (float*)d_ws;                 // 4094 entries x 80 floats = 1.31 MB
  float* st2 = (float*)d_ws + 393216;        // 33.5 MB level-7 state [j][t][h][b]
  float* st1 = (float*)d_out;                // 33.5 MB level-4 state (KC overwrites d_out)
  float* out = (float*)d_out;

  bfly_prep<<<dim3(1088), dim3(256), 0, stream>>>(P, wt);
  bfly_ka<<<dim3(1024), dim3(512), 0, stream>>>(x, wt, st1);
  bfly_kb<<<dim3(8, 128), dim3(512), 0, stream>>>(st1, wt, st2);
  bfly_kc<<<dim3(128, 16), dim3(512), 0, stream>>>(st2, wt, fea, out);
}